// Round 4
// baseline (504.077 us; speedup 1.0000x reference)
//
#include <hip/hip_runtime.h>
#include <stdint.h>
#include <stddef.h>

// QuestionSpecificMLP: counting-sort by routed head index, then fused
// bf16-MFMA trunk + fp32 routed head, with software-pipelined (depth-2 x,
// depth-1 W) k-loops to hide HBM/L2 load latency behind MFMA phases.

typedef short s8v __attribute__((ext_vector_type(8)));   // 8 bf16 (4 VGPRs)
typedef float f4v __attribute__((ext_vector_type(4)));   // MFMA acc
typedef float f4a __attribute__((ext_vector_type(4), aligned(4)));  // unaligned-ok float4

namespace {
constexpr int kDin = 385;
constexpr int kDh  = 192;
constexpr int kQ   = 1000;
constexpr int kC   = 16;
constexpr int BM   = 64;
constexpr int NT   = 256;
constexpr int NK1  = 13;          // ceil(385/32), zero-padded
constexpr int NK2  = 6;           // 192/32
constexpr int CHUNK = 12 * 64 * 8;   // 6144 bf16 per swizzled k-chunk
constexpr int H2   = 200;         // bf16 stride for h / feat rows

// workspace layout (bytes)
constexpr size_t WS_W1   = 0;        // 159744
constexpr size_t WS_W2   = 163840;   // 73728
constexpr size_t WS_HIST = 245760;   // 2048*4
constexpr size_t WS_CUR  = 253952;   // 2048*4
constexpr size_t WS_PERM = 262144;   // 131072*4 -> ends at 768 KB
}

__device__ __forceinline__ unsigned short f2bf(float f) {
  unsigned int u = __float_as_uint(f);
  u = u + 0x7fffu + ((u >> 16) & 1u);       // RNE (non-NaN inputs)
  return (unsigned short)(u >> 16);
}
__device__ __forceinline__ float bf2f(short h) {
  return __uint_as_float(((unsigned int)(unsigned short)h) << 16);
}

// ---- combined prep: histogram + both weight swizzles ---------------------
// blocks [0, nbH)            : histogram of head indices
// blocks [nbH, nbH+312)      : W1 swizzle (NK1*CHUNK = 79872 = 312*256)
// blocks [nbH+312, nbH+456)  : W2 swizzle (NK2*CHUNK = 36864 = 144*256)
__device__ __forceinline__ void swz_one(const float* W, int K, int idx,
                                        unsigned short* out) {
  int j  = idx & 7;
  int l  = (idx >> 3) & 63;
  int rem = idx % CHUNK;
  int t  = rem >> 9;
  int kk = idx / CHUNK;
  int k  = kk * 32 + ((l >> 4) << 3) + j;
  int c  = t * 16 + (l & 15);
  float v = (k < K) ? W[(size_t)k * kDh + c] : 0.f;
  out[idx] = f2bf(v);
}

__global__ void combo_prep(const int* __restrict__ qid, const int* __restrict__ isc,
                           int B, int nbH,
                           const float* __restrict__ W1, const float* __restrict__ W2,
                           int* __restrict__ hist,
                           unsigned short* __restrict__ W1sw,
                           unsigned short* __restrict__ W2sw) {
  int bid = blockIdx.x;
  if (bid < nbH) {
    int i = bid * 256 + threadIdx.x;
    if (i < B) atomicAdd(&hist[qid[i] + isc[i] * kQ], 1);
  } else if (bid < nbH + 312) {
    swz_one(W1, kDin, (bid - nbH) * 256 + threadIdx.x, W1sw);
  } else {
    swz_one(W2, kDh, (bid - nbH - 312) * 256 + threadIdx.x, W2sw);
  }
}

__global__ void scan_k(const int* __restrict__ hist, int* __restrict__ cursor) {
  __shared__ int s[2048];
  int t = threadIdx.x;
  s[t] = hist[t]; s[t + 1024] = hist[t + 1024];
  __syncthreads();
  for (int d = 1; d < 2048; d <<= 1) {
    int a0 = (t >= d) ? s[t - d] : 0;
    int a1 = (t + 1024 >= d) ? s[t + 1024 - d] : 0;
    __syncthreads();
    s[t] += a0; s[t + 1024] += a1;
    __syncthreads();
  }
  cursor[t] = s[t] - hist[t];                       // exclusive prefix
  cursor[t + 1024] = s[t + 1024] - hist[t + 1024];
}

__global__ void scatter_k(const int* __restrict__ qid, const int* __restrict__ isc,
                          int B, int* __restrict__ cursor, int* __restrict__ perm) {
  int i = blockIdx.x * blockDim.x + threadIdx.x;
  if (i < B) {
    int h = qid[i] + isc[i] * kQ;
    int pos = atomicAdd(&cursor[h], 1);
    perm[pos] = i;
  }
}

// ---- main fused kernel ---------------------------------------------------
__global__ __launch_bounds__(NT, 4)
void fused_qmlp4(const float* __restrict__ x,
                 const int*   __restrict__ qid,
                 const int*   __restrict__ isc,
                 const float* __restrict__ b1,
                 const float* __restrict__ b2,
                 const float* __restrict__ Wh,
                 const float* __restrict__ bh,
                 const unsigned short* __restrict__ W1sw,
                 const unsigned short* __restrict__ W2sw,
                 const int*   __restrict__ perm,
                 float* __restrict__ out) {
  __shared__ __align__(16) unsigned short hS[BM * H2];  // 25600 B; h then feat
  __shared__ __align__(16) unsigned short bS[CHUNK];    // 12288 B
  __shared__ int permS[BM];
  __shared__ int idxS[BM];

  const int tid  = threadIdx.x;
  const int lane = tid & 63, wid = tid >> 6;
  const int m = lane & 15, quad = lane >> 4;
  const int rh = wid & 1, ch = wid >> 1;
  const int row0 = blockIdx.x * BM;

  if (tid < BM) {
    int p = perm[row0 + tid];
    permS[tid] = p;
    idxS[tid] = qid[p] + isc[p] * kQ;
  }

  // bias preload (hidden under the sync + first loads)
  float bb1[6], bb2[6];
  #pragma unroll
  for (int t = 0; t < 6; ++t) {
    bb1[t] = b1[ch * 96 + t * 16 + m];
    bb2[t] = b2[ch * 96 + t * 16 + m];
  }
  __syncthreads();

  const size_t xr0 = (size_t)permS[rh * 32 + m] * kDin;
  const size_t xr1 = (size_t)permS[rh * 32 + m + 16] * kDin;

  f4v acc0[6], acc1[6];
  #pragma unroll
  for (int t = 0; t < 6; ++t) {
    acc0[t] = (f4v){0.f, 0.f, 0.f, 0.f};
    acc1[t] = (f4v){0.f, 0.f, 0.f, 0.f};
  }

  // pipeline registers
  f4a xb[2][4];       // [slot][row0 lo, row0 hi, row1 lo, row1 hi]
  s8v wb[2][3];

  // x loader: k-step kk covers k = kk*32 + quad*8 + j. Tail (kk==12): only
  // k==384 valid; load it scalar (avoids OOB read past the last x row).
  auto LDX = [&](int kk, f4a* dst) {
    if (kk < NK1 - 1) {
      const float* p0 = x + xr0 + kk * 32 + quad * 8;
      const float* p1 = x + xr1 + kk * 32 + quad * 8;
      dst[0] = *(const f4a*)p0;
      dst[1] = *(const f4a*)(p0 + 4);
      dst[2] = *(const f4a*)p1;
      dst[3] = *(const f4a*)(p1 + 4);
    } else {
      float v0 = (quad == 0) ? x[xr0 + 384] : 0.f;
      float v1 = (quad == 0) ? x[xr1 + 384] : 0.f;
      dst[0] = (f4a){v0, 0.f, 0.f, 0.f};
      dst[1] = (f4a){0.f, 0.f, 0.f, 0.f};
      dst[2] = (f4a){v1, 0.f, 0.f, 0.f};
      dst[3] = (f4a){0.f, 0.f, 0.f, 0.f};
    }
  };
  auto LDW1 = [&](int kk, s8v* dst) {
    const s8v* s_ = (const s8v*)(W1sw + (size_t)kk * CHUNK);
    dst[0] = s_[tid]; dst[1] = s_[tid + NT]; dst[2] = s_[tid + 2 * NT];
  };
  auto LDW2 = [&](int kk, s8v* dst) {
    const s8v* s_ = (const s8v*)(W2sw + (size_t)kk * CHUNK);
    dst[0] = s_[tid]; dst[1] = s_[tid + NT]; dst[2] = s_[tid + 2 * NT];
  };

  // ---------------- layer 1: h = relu(x @ W1 + b1), K padded to 416 --------
  LDX(0, xb[0]);
  LDW1(0, wb[0]);
  LDX(1, xb[1]);

  #pragma unroll
  for (int kk = 0; kk < NK1; ++kk) {
    const int cur = kk & 1, nxt = cur ^ 1;
    if (kk + 1 < NK1) LDW1(kk + 1, wb[nxt]);        // W prefetch (L2-resident)

    ((s8v*)bS)[tid] = wb[cur][0];                   // waits on W(kk) only
    ((s8v*)bS)[tid + NT] = wb[cur][1];
    ((s8v*)bS)[tid + 2 * NT] = wb[cur][2];

    s8v a0, a1;                                     // waits on x(kk) only
    #pragma unroll
    for (int j = 0; j < 4; ++j) {
      a0[j]     = (short)f2bf(xb[cur][0][j]);
      a0[j + 4] = (short)f2bf(xb[cur][1][j]);
      a1[j]     = (short)f2bf(xb[cur][2][j]);
      a1[j + 4] = (short)f2bf(xb[cur][3][j]);
    }
    if (kk + 2 < NK1) LDX(kk + 2, xb[cur]);         // x prefetch, depth 2 (HBM)

    __syncthreads();
    #pragma unroll
    for (int t = 0; t < 6; ++t) {
      s8v b = *(const s8v*)&bS[((ch * 6 + t) * 64 + lane) * 8];
      acc0[t] = __builtin_amdgcn_mfma_f32_16x16x32_bf16(a0, b, acc0[t], 0, 0, 0);
      acc1[t] = __builtin_amdgcn_mfma_f32_16x16x32_bf16(a1, b, acc1[t], 0, 0, 0);
    }
    __syncthreads();
  }

  // epilogue 1: bias + relu, h -> LDS bf16 row-major
  #pragma unroll
  for (int t = 0; t < 6; ++t) {
    int c = ch * 96 + t * 16 + m;
    #pragma unroll
    for (int r4 = 0; r4 < 4; ++r4) {
      int r = rh * 32 + quad * 4 + r4;
      float v0 = acc0[t][r4] + bb1[t]; v0 = v0 > 0.f ? v0 : 0.f;
      hS[r * H2 + c] = f2bf(v0);
      float v1 = acc1[t][r4] + bb1[t]; v1 = v1 > 0.f ? v1 : 0.f;
      hS[(r + 16) * H2 + c] = f2bf(v1);
      acc0[t][r4] = 0.f;
      acc1[t][r4] = 0.f;
    }
  }

  // ---------------- layer 2: feat = relu(h @ W2 + b2) ----------------------
  const int ar0 = (rh * 32 + m) * H2;
  LDW2(0, wb[0]);
  #pragma unroll
  for (int kk = 0; kk < NK2; ++kk) {
    const int cur = kk & 1, nxt = cur ^ 1;
    if (kk + 1 < NK2) LDW2(kk + 1, wb[nxt]);

    ((s8v*)bS)[tid] = wb[cur][0];
    ((s8v*)bS)[tid + NT] = wb[cur][1];
    ((s8v*)bS)[tid + 2 * NT] = wb[cur][2];
    __syncthreads();                                // fences epilogue-1 hS too

    s8v a0 = *(const s8v*)&hS[ar0 + kk * 32 + quad * 8];
    s8v a1 = *(const s8v*)&hS[ar0 + 16 * H2 + kk * 32 + quad * 8];
    #pragma unroll
    for (int t = 0; t < 6; ++t) {
      s8v b = *(const s8v*)&bS[((ch * 6 + t) * 64 + lane) * 8];
      acc0[t] = __builtin_amdgcn_mfma_f32_16x16x32_bf16(a0, b, acc0[t], 0, 0, 0);
      acc1[t] = __builtin_amdgcn_mfma_f32_16x16x32_bf16(a1, b, acc1[t], 0, 0, 0);
    }
    __syncthreads();
  }

  // epilogue 2: bias + relu, feat (bf16) overwrites h region
  #pragma unroll
  for (int t = 0; t < 6; ++t) {
    int c = ch * 96 + t * 16 + m;
    #pragma unroll
    for (int r4 = 0; r4 < 4; ++r4) {
      int r = rh * 32 + quad * 4 + r4;
      float v0 = acc0[t][r4] + bb2[t];
      hS[r * H2 + c] = f2bf(v0 > 0.f ? v0 : 0.f);
      float v1 = acc1[t][r4] + bb2[t];
      hS[(r + 16) * H2 + c] = f2bf(v1 > 0.f ? v1 : 0.f);
    }
  }
  __syncthreads();

  // ---------------- routed head (fp32 weights, bf16 feat) ------------------
  const int cls = lane >> 2, qp = lane & 3;   // 16 classes x 4 k-quarters
  #pragma unroll 2
  for (int rr = 0; rr < 16; ++rr) {
    int row = wid * 16 + rr;
    int hidx = idxS[row];
    int g = permS[row];
    const float4* wp = (const float4*)(Wh + ((size_t)hidx * kC + cls) * kDh + qp * 48);
    const unsigned short* fr = &hS[row * H2 + qp * 48];
    float s = 0.f;
    #pragma unroll
    for (int t = 0; t < 6; ++t) {
      s8v f8 = *(const s8v*)&fr[t * 8];
      float4 wA = wp[2 * t], wB = wp[2 * t + 1];
      s += wA.x * bf2f(f8[0]) + wA.y * bf2f(f8[1]) +
           wA.z * bf2f(f8[2]) + wA.w * bf2f(f8[3]);
      s += wB.x * bf2f(f8[4]) + wB.y * bf2f(f8[5]) +
           wB.z * bf2f(f8[6]) + wB.w * bf2f(f8[7]);
    }
    s += __shfl_xor(s, 1);
    s += __shfl_xor(s, 2);
    if (qp == 0)
      out[(size_t)g * kC + cls] = s + bh[(size_t)hidx * kC + cls];
  }
}

extern "C" void kernel_launch(void* const* d_in, const int* in_sizes, int n_in,
                              void* d_out, int out_size, void* d_ws, size_t ws_size,
                              hipStream_t stream) {
  const float* x  = (const float*)d_in[0];
  const int*   qd = (const int*)  d_in[1];
  const int*   ic = (const int*)  d_in[2];
  const float* W1 = (const float*)d_in[3];
  const float* b1 = (const float*)d_in[4];
  const float* W2 = (const float*)d_in[5];
  const float* b2 = (const float*)d_in[6];
  const float* Wh = (const float*)d_in[7];
  const float* bh = (const float*)d_in[8];
  float* out = (float*)d_out;

  char* ws = (char*)d_ws;
  unsigned short* W1sw = (unsigned short*)(ws + WS_W1);
  unsigned short* W2sw = (unsigned short*)(ws + WS_W2);
  int* hist   = (int*)(ws + WS_HIST);
  int* cursor = (int*)(ws + WS_CUR);
  int* perm   = (int*)(ws + WS_PERM);

  int B = in_sizes[1];   // 131072
  int nbH = (B + 255) / 256;

  hipMemsetAsync(hist, 0, 2048 * sizeof(int), stream);
  combo_prep<<<nbH + 312 + 144, 256, 0, stream>>>(qd, ic, B, nbH, W1, W2,
                                                  hist, W1sw, W2sw);
  scan_k<<<1, 1024, 0, stream>>>(hist, cursor);
  scatter_k<<<(B + 255) / 256, 256, 0, stream>>>(qd, ic, B, cursor, perm);

  fused_qmlp4<<<B / BM, NT, 0, stream>>>(x, qd, ic, b1, b2, Wh, bh,
                                         W1sw, W2sw, perm, out);
}

// Round 5
// 398.206 us; speedup vs baseline: 1.2659x; 1.2659x over previous
//
#include <hip/hip_runtime.h>
#include <stdint.h>
#include <stddef.h>

// QuestionSpecificMLP: counting-sort by routed head index + fused bf16-MFMA
// trunk. R5: head phase is per-(wave,run) MFMA — B-fragment built once per
// distinct head (12 coalesced-ish float4 loads) instead of 192 scattered
// per-lane loads per wave (R3's L1-transaction bottleneck, ~76% of time).

typedef short s8v __attribute__((ext_vector_type(8)));   // 8 bf16 (4 VGPRs)
typedef float f4v __attribute__((ext_vector_type(4)));   // MFMA acc
typedef float f4a __attribute__((ext_vector_type(4), aligned(4)));  // 4B-aligned float4

namespace {
constexpr int kDin = 385;
constexpr int kDh  = 192;
constexpr int kQ   = 1000;
constexpr int kC   = 16;
constexpr int BM   = 64;
constexpr int NT   = 256;
constexpr int NK1  = 13;          // ceil(385/32), zero-padded
constexpr int NK2  = 6;           // 192/32
constexpr int CHUNK = 12 * 64 * 8;   // 6144 bf16 per swizzled k-chunk
constexpr int H2   = 200;         // bf16 stride for h / feat rows

// workspace layout (bytes)
constexpr size_t WS_W1   = 0;        // 159744
constexpr size_t WS_W2   = 163840;   // 73728
constexpr size_t WS_HIST = 245760;   // 2048*4
constexpr size_t WS_CUR  = 253952;   // 2048*4
constexpr size_t WS_PERM = 262144;   // 131072*4 -> ends at 768 KB
}

__device__ __forceinline__ unsigned short f2bf(float f) {
  unsigned int u = __float_as_uint(f);
  u = u + 0x7fffu + ((u >> 16) & 1u);       // RNE (non-NaN inputs)
  return (unsigned short)(u >> 16);
}

// ---- combined prep: histogram + both weight swizzles ---------------------
// Coalesced-read swizzle: thread i reads W[k][c] with c fastest, computes the
// B-fragment output index. out[(k>>5)*CHUNK + ((c>>4)*64+((k>>3)&3)*16+(c&15))*8+(k&7)]
__device__ __forceinline__ void swz_one(const float* W, int K, int i,
                                        unsigned short* out) {
  int k = i / kDh;
  int c = i - k * kDh;
  float v = (k < K) ? W[(size_t)k * kDh + c] : 0.f;
  int oi = (k >> 5) * CHUNK + (((c >> 4) * 64 + ((k >> 3) & 3) * 16 + (c & 15)) << 3)
         + (k & 7);
  out[oi] = f2bf(v);
}

__global__ void combo_prep(const int* __restrict__ qid, const int* __restrict__ isc,
                           int B, int nbH,
                           const float* __restrict__ W1, const float* __restrict__ W2,
                           int* __restrict__ hist,
                           unsigned short* __restrict__ W1sw,
                           unsigned short* __restrict__ W2sw) {
  int bid = blockIdx.x;
  if (bid < nbH) {
    int i = bid * 256 + threadIdx.x;
    if (i < B) atomicAdd(&hist[qid[i] + isc[i] * kQ], 1);
  } else if (bid < nbH + 312) {                       // 312*256 = 416*192
    swz_one(W1, kDin, (bid - nbH) * 256 + threadIdx.x, W1sw);
  } else {                                            // 144*256 = 192*192
    swz_one(W2, kDh, (bid - nbH - 312) * 256 + threadIdx.x, W2sw);
  }
}

__global__ void scan_k(const int* __restrict__ hist, int* __restrict__ cursor) {
  __shared__ int s[2048];
  int t = threadIdx.x;
  s[t] = hist[t]; s[t + 1024] = hist[t + 1024];
  __syncthreads();
  for (int d = 1; d < 2048; d <<= 1) {
    int a0 = (t >= d) ? s[t - d] : 0;
    int a1 = (t + 1024 >= d) ? s[t + 1024 - d] : 0;
    __syncthreads();
    s[t] += a0; s[t + 1024] += a1;
    __syncthreads();
  }
  cursor[t] = s[t] - hist[t];                       // exclusive prefix
  cursor[t + 1024] = s[t + 1024] - hist[t + 1024];
}

__global__ void scatter_k(const int* __restrict__ qid, const int* __restrict__ isc,
                          int B, int* __restrict__ cursor, int* __restrict__ perm) {
  int i = blockIdx.x * blockDim.x + threadIdx.x;
  if (i < B) {
    int h = qid[i] + isc[i] * kQ;
    int pos = atomicAdd(&cursor[h], 1);
    perm[pos] = i;
  }
}

// ---- main fused kernel ---------------------------------------------------
__global__ __launch_bounds__(NT, 4)
void fused_qmlp5(const float* __restrict__ x,
                 const int*   __restrict__ qid,
                 const int*   __restrict__ isc,
                 const float* __restrict__ b1,
                 const float* __restrict__ b2,
                 const float* __restrict__ Wh,
                 const float* __restrict__ bh,
                 const unsigned short* __restrict__ W1sw,
                 const unsigned short* __restrict__ W2sw,
                 const int*   __restrict__ perm,
                 float* __restrict__ out) {
  __shared__ __align__(16) unsigned short hS[BM * H2];  // 25600 B; h then feat
  __shared__ __align__(16) unsigned short bS[CHUNK];    // 12288 B
  __shared__ int permS[BM];
  __shared__ int idxS[BM];

  const int tid  = threadIdx.x;
  const int lane = tid & 63, wid = tid >> 6;
  const int m = lane & 15, quad = lane >> 4;
  const int rh = wid & 1, ch = wid >> 1;
  const int row0 = blockIdx.x * BM;

  if (tid < BM) {
    int p = perm[row0 + tid];
    permS[tid] = p;
    idxS[tid] = qid[p] + isc[p] * kQ;
  }
  __syncthreads();

  const size_t xr0 = (size_t)permS[rh * 32 + m] * kDin;
  const size_t xr1 = (size_t)permS[rh * 32 + m + 16] * kDin;

  f4v acc0[6], acc1[6];
  #pragma unroll
  for (int t = 0; t < 6; ++t) {
    acc0[t] = (f4v){0.f, 0.f, 0.f, 0.f};
    acc1[t] = (f4v){0.f, 0.f, 0.f, 0.f};
  }

  // ---------------- layer 1: h = relu(x @ W1 + b1), K padded to 416 --------
  for (int kk = 0; kk < NK1; ++kk) {
    const s8v* src = (const s8v*)(W1sw + (size_t)kk * CHUNK);
    s8v w0 = src[tid], w1 = src[tid + NT], w2 = src[tid + 2 * NT];

    s8v a0, a1;
    if (kk < NK1 - 1) {                       // k = kk*32 + quad*8 + j, all < 384
      const float* p0 = x + xr0 + kk * 32 + quad * 8;
      const float* p1 = x + xr1 + kk * 32 + quad * 8;
      f4a v00 = *(const f4a*)p0, v01 = *(const f4a*)(p0 + 4);
      f4a v10 = *(const f4a*)p1, v11 = *(const f4a*)(p1 + 4);
      #pragma unroll
      for (int j = 0; j < 4; ++j) {
        a0[j]     = (short)f2bf(v00[j]);
        a0[j + 4] = (short)f2bf(v01[j]);
        a1[j]     = (short)f2bf(v10[j]);
        a1[j + 4] = (short)f2bf(v11[j]);
      }
    } else {                                  // only k==384 valid (quad 0, j 0)
      float v0 = (quad == 0) ? x[xr0 + 384] : 0.f;
      float v1 = (quad == 0) ? x[xr1 + 384] : 0.f;
      a0 = (s8v){0,0,0,0,0,0,0,0};
      a1 = (s8v){0,0,0,0,0,0,0,0};
      a0[0] = (short)f2bf(v0);
      a1[0] = (short)f2bf(v1);
    }

    ((s8v*)bS)[tid] = w0;
    ((s8v*)bS)[tid + NT] = w1;
    ((s8v*)bS)[tid + 2 * NT] = w2;
    __syncthreads();

    #pragma unroll
    for (int t = 0; t < 6; ++t) {
      s8v b = *(const s8v*)&bS[((ch * 6 + t) * 64 + lane) * 8];
      acc0[t] = __builtin_amdgcn_mfma_f32_16x16x32_bf16(a0, b, acc0[t], 0, 0, 0);
      acc1[t] = __builtin_amdgcn_mfma_f32_16x16x32_bf16(a1, b, acc1[t], 0, 0, 0);
    }
    __syncthreads();
  }

  // epilogue 1: bias + relu, h -> LDS bf16 row-major
  #pragma unroll
  for (int t = 0; t < 6; ++t) {
    int c = ch * 96 + t * 16 + m;
    float bb = b1[c];
    #pragma unroll
    for (int r4 = 0; r4 < 4; ++r4) {
      int r = rh * 32 + quad * 4 + r4;
      float v0 = acc0[t][r4] + bb; v0 = v0 > 0.f ? v0 : 0.f;
      hS[r * H2 + c] = f2bf(v0);
      float v1 = acc1[t][r4] + bb; v1 = v1 > 0.f ? v1 : 0.f;
      hS[(r + 16) * H2 + c] = f2bf(v1);
      acc0[t][r4] = 0.f;
      acc1[t][r4] = 0.f;
    }
  }

  // ---------------- layer 2: feat = relu(h @ W2 + b2) ----------------------
  const int ar0 = (rh * 32 + m) * H2;
  for (int kk = 0; kk < NK2; ++kk) {
    const s8v* src = (const s8v*)(W2sw + (size_t)kk * CHUNK);
    s8v w0 = src[tid], w1 = src[tid + NT], w2 = src[tid + 2 * NT];
    ((s8v*)bS)[tid] = w0;
    ((s8v*)bS)[tid + NT] = w1;
    ((s8v*)bS)[tid + 2 * NT] = w2;
    __syncthreads();                          // fences epilogue-1 hS writes too

    s8v a0 = *(const s8v*)&hS[ar0 + kk * 32 + quad * 8];
    s8v a1 = *(const s8v*)&hS[ar0 + 16 * H2 + kk * 32 + quad * 8];
    #pragma unroll
    for (int t = 0; t < 6; ++t) {
      s8v b = *(const s8v*)&bS[((ch * 6 + t) * 64 + lane) * 8];
      acc0[t] = __builtin_amdgcn_mfma_f32_16x16x32_bf16(a0, b, acc0[t], 0, 0, 0);
      acc1[t] = __builtin_amdgcn_mfma_f32_16x16x32_bf16(a1, b, acc1[t], 0, 0, 0);
    }
    __syncthreads();
  }

  // epilogue 2: bias + relu, feat (bf16) overwrites h region
  #pragma unroll
  for (int t = 0; t < 6; ++t) {
    int c = ch * 96 + t * 16 + m;
    float bb = b2[c];
    #pragma unroll
    for (int r4 = 0; r4 < 4; ++r4) {
      int r = rh * 32 + quad * 4 + r4;
      float v0 = acc0[t][r4] + bb;
      hS[r * H2 + c] = f2bf(v0 > 0.f ? v0 : 0.f);
      float v1 = acc1[t][r4] + bb;
      hS[(r + 16) * H2 + c] = f2bf(v1 > 0.f ? v1 : 0.f);
    }
  }
  __syncthreads();

  // ---------------- routed head via MFMA, one pass per distinct head -------
  // Wave w owns rows [w*16, w*16+16). out[rows][16] = feat @ Wq[h]^T + bh[h].
  // B[k][n] = Wq[n][k]: lane (n=lane&15, quad) reads Wq row n, k=quad*8+j.
  // A masked per-lane to the head's run; D-layout store masked by run bits.
  {
    const int w16 = wid * 16;
    const int hm = idxS[w16 + m];             // head of this lane's A-row
    unsigned rem = 0xFFFFu;
    while (rem) {
      int r0 = (int)__builtin_ctz(rem);
      int h = idxS[w16 + r0];                 // uniform (LDS broadcast)
      unsigned long long bal = __ballot(hm == h);
      unsigned mask16 = (unsigned)(bal & 0xFFFFu);
      rem &= ~mask16;
      bool valid = (hm == h);

      const float* wq = Wh + ((size_t)h * kC + m) * kDh + quad * 8;
      f4v acc = (f4v){0.f, 0.f, 0.f, 0.f};
      #pragma unroll
      for (int kk = 0; kk < 6; ++kk) {
        float4 wlo = *(const float4*)(wq + kk * 32);
        float4 whi = *(const float4*)(wq + kk * 32 + 4);
        s8v bfr;
        bfr[0] = (short)f2bf(wlo.x); bfr[1] = (short)f2bf(wlo.y);
        bfr[2] = (short)f2bf(wlo.z); bfr[3] = (short)f2bf(wlo.w);
        bfr[4] = (short)f2bf(whi.x); bfr[5] = (short)f2bf(whi.y);
        bfr[6] = (short)f2bf(whi.z); bfr[7] = (short)f2bf(whi.w);
        s8v afr = *(const s8v*)&hS[(w16 + m) * H2 + kk * 32 + quad * 8];
        if (!valid) afr = (s8v){0,0,0,0,0,0,0,0};
        acc = __builtin_amdgcn_mfma_f32_16x16x32_bf16(afr, bfr, acc, 0, 0, 0);
      }
      float bhv = bh[(size_t)h * kC + m];
      #pragma unroll
      for (int reg = 0; reg < 4; ++reg) {
        int r = quad * 4 + reg;
        if ((mask16 >> r) & 1u)
          out[(size_t)permS[w16 + r] * kC + m] = acc[reg] + bhv;
      }
    }
  }
}

extern "C" void kernel_launch(void* const* d_in, const int* in_sizes, int n_in,
                              void* d_out, int out_size, void* d_ws, size_t ws_size,
                              hipStream_t stream) {
  const float* x  = (const float*)d_in[0];
  const int*   qd = (const int*)  d_in[1];
  const int*   ic = (const int*)  d_in[2];
  const float* W1 = (const float*)d_in[3];
  const float* b1 = (const float*)d_in[4];
  const float* W2 = (const float*)d_in[5];
  const float* b2 = (const float*)d_in[6];
  const float* Wh = (const float*)d_in[7];
  const float* bh = (const float*)d_in[8];
  float* out = (float*)d_out;

  char* ws = (char*)d_ws;
  unsigned short* W1sw = (unsigned short*)(ws + WS_W1);
  unsigned short* W2sw = (unsigned short*)(ws + WS_W2);
  int* hist   = (int*)(ws + WS_HIST);
  int* cursor = (int*)(ws + WS_CUR);
  int* perm   = (int*)(ws + WS_PERM);

  int B = in_sizes[1];   // 131072
  int nbH = (B + 255) / 256;

  hipMemsetAsync(hist, 0, 2048 * sizeof(int), stream);
  combo_prep<<<nbH + 312 + 144, 256, 0, stream>>>(qd, ic, B, nbH, W1, W2,
                                                  hist, W1sw, W2sw);
  scan_k<<<1, 1024, 0, stream>>>(hist, cursor);
  scatter_k<<<(B + 255) / 256, 256, 0, stream>>>(qd, ic, B, cursor, perm);

  fused_qmlp5<<<B / BM, NT, 0, stream>>>(x, qd, ic, b1, b2, Wh, bh,
                                         W1sw, W2sw, perm, out);
}